// Round 1
// baseline (484.896 us; speedup 1.0000x reference)
//
#include <hip/hip_runtime.h>
#include <hip/hip_bf16.h>

// Problem constants (match reference)
constexpr int N_NODES = 50000;
constexpr int N_EDGES = 600000;
constexpr int D       = 128;   // IN_DIM == FEAT
constexpr int N_CLS   = 40;

// ---------------------------------------------------------------------------
// CSR build: histogram -> block scan -> sum scan -> finalize -> scatter
// ---------------------------------------------------------------------------

__global__ void hist_kernel(const int* __restrict__ ei, int* __restrict__ cnt) {
    int e = blockIdx.x * 256 + threadIdx.x;
    if (e < N_EDGES) atomicAdd(&cnt[ei[N_EDGES + e]], 1);
}

__global__ __launch_bounds__(1024) void scan_block_kernel(const int* __restrict__ cnt,
                                                          int* __restrict__ rs,
                                                          int* __restrict__ bsum, int n) {
    __shared__ int t[1024];
    int tid = threadIdx.x;
    int gid = blockIdx.x * 1024 + tid;
    int v = (gid < n) ? cnt[gid] : 0;
    t[tid] = v;
    __syncthreads();
    for (int off = 1; off < 1024; off <<= 1) {
        int u = (tid >= off) ? t[tid - off] : 0;
        __syncthreads();
        t[tid] += u;
        __syncthreads();
    }
    if (gid < n) rs[gid] = t[tid] - v;          // exclusive within block
    if (tid == 1023) bsum[blockIdx.x] = t[1023];
}

__global__ void scan_sums_kernel(const int* __restrict__ bsum, int* __restrict__ boff, int nblk) {
    __shared__ int t[64];
    int tid = threadIdx.x;
    int v = (tid < nblk) ? bsum[tid] : 0;
    t[tid] = v;
    __syncthreads();
    for (int off = 1; off < 64; off <<= 1) {
        int u = (tid >= off) ? t[tid - off] : 0;
        __syncthreads();
        t[tid] += u;
        __syncthreads();
    }
    if (tid < nblk) boff[tid] = t[tid] - v;     // exclusive
}

__global__ void finalize_kernel(const int* __restrict__ cnt, int* __restrict__ rs,
                                int* __restrict__ cursor, float* __restrict__ dinv,
                                const int* __restrict__ boff) {
    int i = blockIdx.x * 256 + threadIdx.x;
    if (i < N_NODES) {
        int v = rs[i] + boff[i >> 10];
        rs[i] = v;
        cursor[i] = v;
        dinv[i] = 1.0f / fmaxf((float)cnt[i], 1.0f);
        if (i == 0) rs[N_NODES] = N_EDGES;
    }
}

__global__ void scatter_kernel(const int* __restrict__ ei, int* __restrict__ cursor,
                               int* __restrict__ csr) {
    int e = blockIdx.x * 256 + threadIdx.x;
    if (e < N_EDGES) {
        int d = ei[N_EDGES + e];
        int p = atomicAdd(&cursor[d], 1);
        csr[p] = ei[e];
    }
}

// ---------------------------------------------------------------------------
// Mean aggregation: one wave (64 lanes) per node; lane holds 2 feature floats.
// Writes aggn = deg_inv * sum(x[src]).
// ---------------------------------------------------------------------------
__global__ __launch_bounds__(256) void agg_kernel(const float* __restrict__ feat,
                                                  const int* __restrict__ rs,
                                                  const int* __restrict__ csr,
                                                  const float* __restrict__ dinv,
                                                  float* __restrict__ aggn) {
    int wave = threadIdx.x >> 6;
    int lane = threadIdx.x & 63;
    int node = blockIdx.x * 4 + wave;
    if (node >= N_NODES) return;
    int e0 = rs[node], e1 = rs[node + 1];
    float ax = 0.f, ay = 0.f;
    int e = e0;
    for (; e + 4 <= e1; e += 4) {
        int s0 = csr[e], s1 = csr[e + 1], s2 = csr[e + 2], s3 = csr[e + 3];
        float2 v0 = *(const float2*)&feat[(size_t)s0 * D + lane * 2];
        float2 v1 = *(const float2*)&feat[(size_t)s1 * D + lane * 2];
        float2 v2 = *(const float2*)&feat[(size_t)s2 * D + lane * 2];
        float2 v3 = *(const float2*)&feat[(size_t)s3 * D + lane * 2];
        ax += v0.x + v1.x + v2.x + v3.x;
        ay += v0.y + v1.y + v2.y + v3.y;
    }
    for (; e < e1; ++e) {
        int s = csr[e];
        float2 v = *(const float2*)&feat[(size_t)s * D + lane * 2];
        ax += v.x; ay += v.y;
    }
    float di = dinv[node];
    float2 o; o.x = ax * di; o.y = ay * di;
    *(float2*)&aggn[(size_t)node * D + lane * 2] = o;
}

// ---------------------------------------------------------------------------
// Fused SAGE linear: out = relu(aggn@Wl^T + bl + Ax@Wr^T) [+ resid]
// Tile: BM=64 rows x BN=128 cols, BK=32. 256 threads, 4x8 micro-tile.
// ---------------------------------------------------------------------------
#define BM 64
#define BKK 32
__global__ __launch_bounds__(256) void gemm_sage_kernel(const float* __restrict__ Aagg,
                                                        const float* __restrict__ Ax,
                                                        const float* __restrict__ Wl,
                                                        const float* __restrict__ Wr,
                                                        const float* __restrict__ bias,
                                                        const float* __restrict__ resid,
                                                        float* __restrict__ outp, int M) {
    __shared__ float As[BKK][BM];        // A transposed: As[k][row]
    __shared__ float Ws[BKK][D + 4];     // W transposed: Ws[k][col], padded

    int tid = threadIdx.x;
    int tx = tid & 15;    // col group: cols tx*8 .. +7
    int ty = tid >> 4;    // row group: rows ty*4 .. +3
    int row0 = blockIdx.x * BM;

    float acc[4][8];
#pragma unroll
    for (int i = 0; i < 4; ++i)
#pragma unroll
        for (int j = 0; j < 8; ++j) acc[i][j] = 0.f;

    for (int phase = 0; phase < 2; ++phase) {
        const float* A = phase ? Ax : Aagg;
        const float* W = phase ? Wr : Wl;
        for (int kt = 0; kt < D; kt += BKK) {
            // A tile: 64x32 floats = 512 float4 slots, 2 per thread
#pragma unroll
            for (int l = 0; l < 2; ++l) {
                int slot = tid + l * 256;
                int r = slot >> 3;
                int kq = slot & 7;
                int gr = row0 + r;
                if (gr >= M) gr = M - 1;
                float4 v = *(const float4*)&A[(size_t)gr * D + kt + kq * 4];
                As[kq * 4 + 0][r] = v.x;
                As[kq * 4 + 1][r] = v.y;
                As[kq * 4 + 2][r] = v.z;
                As[kq * 4 + 3][r] = v.w;
            }
            // W tile: 128x32 floats = 1024 float4 slots, 4 per thread
#pragma unroll
            for (int l = 0; l < 4; ++l) {
                int slot = tid + l * 256;
                int f = slot >> 3;
                int kq = slot & 7;
                float4 v = *(const float4*)&W[f * D + kt + kq * 4];
                Ws[kq * 4 + 0][f] = v.x;
                Ws[kq * 4 + 1][f] = v.y;
                Ws[kq * 4 + 2][f] = v.z;
                Ws[kq * 4 + 3][f] = v.w;
            }
            __syncthreads();
#pragma unroll 8
            for (int kk = 0; kk < BKK; ++kk) {
                float4 a  = *(const float4*)&As[kk][ty * 4];
                float4 w0 = *(const float4*)&Ws[kk][tx * 8];
                float4 w1 = *(const float4*)&Ws[kk][tx * 8 + 4];
                float av[4] = {a.x, a.y, a.z, a.w};
                float wv[8] = {w0.x, w0.y, w0.z, w0.w, w1.x, w1.y, w1.z, w1.w};
#pragma unroll
                for (int i = 0; i < 4; ++i)
#pragma unroll
                    for (int j = 0; j < 8; ++j)
                        acc[i][j] = fmaf(av[i], wv[j], acc[i][j]);
            }
            __syncthreads();
        }
    }

    // epilogue: bias + relu (+ residual), vectorized stores
    float4 b0 = *(const float4*)&bias[tx * 8];
    float4 b1 = *(const float4*)&bias[tx * 8 + 4];
#pragma unroll
    for (int i = 0; i < 4; ++i) {
        int r = row0 + ty * 4 + i;
        if (r >= M) continue;
        float4 o0, o1;
        o0.x = fmaxf(acc[i][0] + b0.x, 0.f);
        o0.y = fmaxf(acc[i][1] + b0.y, 0.f);
        o0.z = fmaxf(acc[i][2] + b0.z, 0.f);
        o0.w = fmaxf(acc[i][3] + b0.w, 0.f);
        o1.x = fmaxf(acc[i][4] + b1.x, 0.f);
        o1.y = fmaxf(acc[i][5] + b1.y, 0.f);
        o1.z = fmaxf(acc[i][6] + b1.z, 0.f);
        o1.w = fmaxf(acc[i][7] + b1.w, 0.f);
        if (resid) {
            float4 r0 = *(const float4*)&resid[(size_t)r * D + tx * 8];
            float4 r1 = *(const float4*)&resid[(size_t)r * D + tx * 8 + 4];
            o0.x += r0.x; o0.y += r0.y; o0.z += r0.z; o0.w += r0.w;
            o1.x += r1.x; o1.y += r1.y; o1.z += r1.z; o1.w += r1.w;
        }
        *(float4*)&outp[(size_t)r * D + tx * 8] = o0;
        *(float4*)&outp[(size_t)r * D + tx * 8 + 4] = o1;
    }
}

// ---------------------------------------------------------------------------
// Classifier: out[M,40] = vif @ Wc^T + bc. 64 rows/block, both operands in LDS.
// Thread: 2 rows x 5 cols.
// ---------------------------------------------------------------------------
__global__ __launch_bounds__(256) void classifier_kernel(const float* __restrict__ vif,
                                                         const float* __restrict__ Wc,
                                                         const float* __restrict__ bc,
                                                         float* __restrict__ outp, int M) {
    __shared__ float Vs[64][D + 4];
    __shared__ float Cs[N_CLS][D + 4];
    int tid = threadIdx.x;
    int row0 = blockIdx.x * 64;

#pragma unroll
    for (int l = 0; l < 8; ++l) {           // 64*32 = 2048 float4 slots
        int slot = tid + l * 256;
        int r = slot >> 5;
        int kq = slot & 31;
        int gr = row0 + r;
        if (gr >= M) gr = M - 1;
        float4 v = *(const float4*)&vif[(size_t)gr * D + kq * 4];
        *(float4*)&Vs[r][kq * 4] = v;
    }
#pragma unroll
    for (int l = 0; l < 5; ++l) {           // 40*32 = 1280 float4 slots
        int slot = tid + l * 256;
        int r = slot >> 5;
        int kq = slot & 31;
        float4 v = *(const float4*)&Wc[r * D + kq * 4];
        *(float4*)&Cs[r][kq * 4] = v;
    }
    __syncthreads();

    int r2 = tid >> 3;   // 0..31 -> rows 2*r2, 2*r2+1
    int cg = tid & 7;    // 0..7  -> cols cg*5 .. +4
    float acc[2][5] = {};
#pragma unroll 4
    for (int k4 = 0; k4 < 32; ++k4) {
        float4 a0 = *(const float4*)&Vs[r2 * 2][k4 * 4];
        float4 a1 = *(const float4*)&Vs[r2 * 2 + 1][k4 * 4];
#pragma unroll
        for (int j = 0; j < 5; ++j) {
            float4 w = *(const float4*)&Cs[cg * 5 + j][k4 * 4];
            acc[0][j] = fmaf(a0.x, w.x, fmaf(a0.y, w.y, fmaf(a0.z, w.z, fmaf(a0.w, w.w, acc[0][j]))));
            acc[1][j] = fmaf(a1.x, w.x, fmaf(a1.y, w.y, fmaf(a1.z, w.z, fmaf(a1.w, w.w, acc[1][j]))));
        }
    }
#pragma unroll
    for (int i = 0; i < 2; ++i) {
        int r = row0 + r2 * 2 + i;
        if (r >= M) continue;
#pragma unroll
        for (int j = 0; j < 5; ++j) {
            int c = cg * 5 + j;
            outp[(size_t)r * N_CLS + c] = acc[i][j] + bc[c];
        }
    }
}

// ---------------------------------------------------------------------------
extern "C" void kernel_launch(void* const* d_in, const int* in_sizes, int n_in,
                              void* d_out, int out_size, void* d_ws, size_t ws_size,
                              hipStream_t stream) {
    const float* x   = (const float*)d_in[0];
    const int*   ei  = (const int*)d_in[1];
    const float* Wl1 = (const float*)d_in[2];
    const float* bl1 = (const float*)d_in[3];
    const float* Wr1 = (const float*)d_in[4];
    const float* Wl2 = (const float*)d_in[5];
    const float* bl2 = (const float*)d_in[6];
    const float* Wr2 = (const float*)d_in[7];
    const float* Wl3 = (const float*)d_in[8];
    const float* bl3 = (const float*)d_in[9];
    const float* Wr3 = (const float*)d_in[10];
    const float* Wc  = (const float*)d_in[11];
    const float* bc  = (const float*)d_in[12];
    float* out = (float*)d_out;

    // workspace carve (256B aligned)
    char* w = (char*)d_ws;
    size_t off = 0;
    auto carve = [&](size_t bytes) -> void* {
        void* p = w + off;
        off = (off + bytes + 255) & ~(size_t)255;
        return p;
    };
    int*   cnt    = (int*)carve((size_t)N_NODES * 4);
    int*   rs     = (int*)carve((size_t)(N_NODES + 1) * 4);
    int*   cursor = (int*)carve((size_t)N_NODES * 4);
    float* dinv   = (float*)carve((size_t)N_NODES * 4);
    int*   bsum   = (int*)carve(64 * 4);
    int*   boff   = (int*)carve(64 * 4);
    int*   csr    = (int*)carve((size_t)N_EDGES * 4);
    float* aggn   = (float*)carve((size_t)N_NODES * D * 4);
    float* bufA   = (float*)carve((size_t)N_NODES * D * 4);  // local, later vif
    float* bufB   = (float*)carve((size_t)N_NODES * D * 4);  // global
    (void)ws_size;

    const int NBLK_SCAN = (N_NODES + 1023) / 1024;           // 49
    const int GRID_E = (N_EDGES + 255) / 256;                // 2344
    const int GRID_N = (N_NODES + 255) / 256;                // 196
    const int GRID_AGG = (N_NODES + 3) / 4;                  // 12500
    const int GRID_GEMM = (N_NODES + BM - 1) / BM;           // 782

    // CSR build
    hipMemsetAsync(cnt, 0, (size_t)N_NODES * 4, stream);
    hipLaunchKernelGGL(hist_kernel, dim3(GRID_E), dim3(256), 0, stream, ei, cnt);
    hipLaunchKernelGGL(scan_block_kernel, dim3(NBLK_SCAN), dim3(1024), 0, stream, cnt, rs, bsum, N_NODES);
    hipLaunchKernelGGL(scan_sums_kernel, dim3(1), dim3(64), 0, stream, bsum, boff, NBLK_SCAN);
    hipLaunchKernelGGL(finalize_kernel, dim3(GRID_N), dim3(256), 0, stream, cnt, rs, cursor, dinv, boff);
    hipLaunchKernelGGL(scatter_kernel, dim3(GRID_E), dim3(256), 0, stream, ei, cursor, csr);

    // Layer 1
    hipLaunchKernelGGL(agg_kernel, dim3(GRID_AGG), dim3(256), 0, stream, x, rs, csr, dinv, aggn);
    hipLaunchKernelGGL(gemm_sage_kernel, dim3(GRID_GEMM), dim3(256), 0, stream,
                       aggn, x, Wl1, Wr1, bl1, (const float*)nullptr, bufA, N_NODES);
    // Layer 2
    hipLaunchKernelGGL(agg_kernel, dim3(GRID_AGG), dim3(256), 0, stream, bufA, rs, csr, dinv, aggn);
    hipLaunchKernelGGL(gemm_sage_kernel, dim3(GRID_GEMM), dim3(256), 0, stream,
                       aggn, bufA, Wl2, Wr2, bl2, (const float*)nullptr, bufB, N_NODES);
    // Layer 3 + residual -> vif (reuse bufA)
    hipLaunchKernelGGL(agg_kernel, dim3(GRID_AGG), dim3(256), 0, stream, bufB, rs, csr, dinv, aggn);
    hipLaunchKernelGGL(gemm_sage_kernel, dim3(GRID_GEMM), dim3(256), 0, stream,
                       aggn, bufB, Wl3, Wr3, bl3, bufB, bufA, N_NODES);
    // Classifier
    hipLaunchKernelGGL(classifier_kernel, dim3(GRID_GEMM), dim3(256), 0, stream,
                       bufA, Wc, bc, out, N_NODES);
}

// Round 2
// 390.958 us; speedup vs baseline: 1.2403x; 1.2403x over previous
//
#include <hip/hip_runtime.h>
#include <hip/hip_bf16.h>

// Problem constants (match reference)
constexpr int N_NODES = 50000;
constexpr int N_EDGES = 600000;
constexpr int D       = 128;   // IN_DIM == FEAT
constexpr int N_CLS   = 40;

using bf16x8 = __attribute__((ext_vector_type(8))) short;   // 8 bf16 = 4 VGPR
using f32x4  = __attribute__((ext_vector_type(4))) float;   // MFMA C/D

__device__ inline unsigned short f2bf(float f) {
    __hip_bfloat16 h = __float2bfloat16(f);
    return __builtin_bit_cast(unsigned short, h);
}
__device__ inline float bf2f(unsigned short u) {
    __hip_bfloat16 h = __builtin_bit_cast(__hip_bfloat16, u);
    return __bfloat162float(h);
}

// ---------------------------------------------------------------------------
// CSR build: histogram -> block scan -> sum scan -> finalize -> scatter
// ---------------------------------------------------------------------------

__global__ void hist_kernel(const int* __restrict__ ei, int* __restrict__ cnt) {
    int e = blockIdx.x * 256 + threadIdx.x;
    if (e < N_EDGES) atomicAdd(&cnt[ei[N_EDGES + e]], 1);
}

__global__ __launch_bounds__(1024) void scan_block_kernel(const int* __restrict__ cnt,
                                                          int* __restrict__ rs,
                                                          int* __restrict__ bsum, int n) {
    __shared__ int t[1024];
    int tid = threadIdx.x;
    int gid = blockIdx.x * 1024 + tid;
    int v = (gid < n) ? cnt[gid] : 0;
    t[tid] = v;
    __syncthreads();
    for (int off = 1; off < 1024; off <<= 1) {
        int u = (tid >= off) ? t[tid - off] : 0;
        __syncthreads();
        t[tid] += u;
        __syncthreads();
    }
    if (gid < n) rs[gid] = t[tid] - v;          // exclusive within block
    if (tid == 1023) bsum[blockIdx.x] = t[1023];
}

__global__ void scan_sums_kernel(const int* __restrict__ bsum, int* __restrict__ boff, int nblk) {
    __shared__ int t[64];
    int tid = threadIdx.x;
    int v = (tid < nblk) ? bsum[tid] : 0;
    t[tid] = v;
    __syncthreads();
    for (int off = 1; off < 64; off <<= 1) {
        int u = (tid >= off) ? t[tid - off] : 0;
        __syncthreads();
        t[tid] += u;
        __syncthreads();
    }
    if (tid < nblk) boff[tid] = t[tid] - v;     // exclusive
}

__global__ void finalize_kernel(const int* __restrict__ cnt, int* __restrict__ rs,
                                int* __restrict__ cursor, float* __restrict__ dinv,
                                const int* __restrict__ boff) {
    int i = blockIdx.x * 256 + threadIdx.x;
    if (i < N_NODES) {
        int v = rs[i] + boff[i >> 10];
        rs[i] = v;
        cursor[i] = v;
        dinv[i] = 1.0f / fmaxf((float)cnt[i], 1.0f);
        if (i == 0) rs[N_NODES] = N_EDGES;
    }
}

__global__ void scatter_kernel(const int* __restrict__ ei, int* __restrict__ cursor,
                               int* __restrict__ csr) {
    int e = blockIdx.x * 256 + threadIdx.x;
    if (e < N_EDGES) {
        int d = ei[N_EDGES + e];
        int p = atomicAdd(&cursor[d], 1);
        csr[p] = ei[e];
    }
}

// ---------------------------------------------------------------------------
// Weight split: Wcat_hi/lo[n][256] bf16 = [ Wl[n][0..127] | Wr[n][0..127] ]
// hi = bf16(w), lo = bf16(w - hi). 128*256 elements, grid 128 x 256.
// ---------------------------------------------------------------------------
__global__ void split_w_kernel(const float* __restrict__ Wl, const float* __restrict__ Wr,
                               unsigned short* __restrict__ hi, unsigned short* __restrict__ lo) {
    int idx = blockIdx.x * 256 + threadIdx.x;   // 0..32767
    int n = idx >> 8, k = idx & 255;
    float v = (k < 128) ? Wl[n * 128 + k] : Wr[n * 128 + (k - 128)];
    unsigned short h = f2bf(v);
    hi[idx] = h;
    lo[idx] = f2bf(v - bf2f(h));
}

// ---------------------------------------------------------------------------
// Mean aggregation: one wave (64 lanes) per node; lane holds 2 feature floats.
// ---------------------------------------------------------------------------
__global__ __launch_bounds__(256) void agg_kernel(const float* __restrict__ feat,
                                                  const int* __restrict__ rs,
                                                  const int* __restrict__ csr,
                                                  const float* __restrict__ dinv,
                                                  float* __restrict__ aggn) {
    int wave = threadIdx.x >> 6;
    int lane = threadIdx.x & 63;
    int node = blockIdx.x * 4 + wave;
    if (node >= N_NODES) return;
    int e0 = rs[node], e1 = rs[node + 1];
    float ax = 0.f, ay = 0.f;
    int e = e0;
    for (; e + 4 <= e1; e += 4) {
        int s0 = csr[e], s1 = csr[e + 1], s2 = csr[e + 2], s3 = csr[e + 3];
        float2 v0 = *(const float2*)&feat[(size_t)s0 * D + lane * 2];
        float2 v1 = *(const float2*)&feat[(size_t)s1 * D + lane * 2];
        float2 v2 = *(const float2*)&feat[(size_t)s2 * D + lane * 2];
        float2 v3 = *(const float2*)&feat[(size_t)s3 * D + lane * 2];
        ax += v0.x + v1.x + v2.x + v3.x;
        ay += v0.y + v1.y + v2.y + v3.y;
    }
    for (; e < e1; ++e) {
        int s = csr[e];
        float2 v = *(const float2*)&feat[(size_t)s * D + lane * 2];
        ax += v.x; ay += v.y;
    }
    float di = dinv[node];
    float2 o; o.x = ax * di; o.y = ay * di;
    *(float2*)&aggn[(size_t)node * D + lane * 2] = o;
}

// ---------------------------------------------------------------------------
// Split-bf16 MFMA GEMM: out = relu([Aagg|Ax] @ Wcat^T + bias) [+ resid]
// Logical K = 256 (k 0..127 from Aagg vs Wl, 128..255 from Ax vs Wr).
// Tile: BM=64 x BN=128, BK=64 (4 k-tiles). 256 threads = 4 waves, each wave
// computes 32 rows x 64 cols = 2x4 fragments of 16x16, mfma_f32_16x16x32_bf16.
// Precision: a ~= ah + al (bf16 each); a*b ~= ah*bh + ah*bl + al*bh (3 MFMA).
// LDS tiles XOR-swizzled (G4: row-major 128B-stride rows = 16-way conflict).
// ---------------------------------------------------------------------------
__global__ __launch_bounds__(256) void gemm_mfma_kernel(const float* __restrict__ Aagg,
                                                        const float* __restrict__ Ax,
                                                        const unsigned short* __restrict__ Whi,
                                                        const unsigned short* __restrict__ Wlo,
                                                        const float* __restrict__ bias,
                                                        const float* __restrict__ resid,
                                                        float* __restrict__ outp, int M) {
    // LDS: A hi/lo 64x64 bf16 (8KB each), W hi/lo 128x64 bf16 (16KB each) = 48KB
    __shared__ __align__(16) unsigned short AhS[64 * 64];
    __shared__ __align__(16) unsigned short AlS[64 * 64];
    __shared__ __align__(16) unsigned short WhS[128 * 64];
    __shared__ __align__(16) unsigned short WlS[128 * 64];
    char* AhB = (char*)AhS;
    char* AlB = (char*)AlS;
    char* WhB = (char*)WhS;
    char* WlB = (char*)WlS;

    int tid = threadIdx.x;
    int lane = tid & 63;
    int wid = tid >> 6;
    int wr = wid >> 1;          // 0..1: row half (32 rows)
    int wc = wid & 1;           // 0..1: col half (64 cols)
    int lr = lane & 15;         // row/col within fragment
    int kg = (lane >> 4) * 8;   // k-group offset within 32-k step
    int row0 = blockIdx.x * 64;

    f32x4 acc[2][4];
#pragma unroll
    for (int f = 0; f < 2; ++f)
#pragma unroll
        for (int j = 0; j < 4; ++j) acc[f][j] = (f32x4){0.f, 0.f, 0.f, 0.f};

    for (int kt = 0; kt < 4; ++kt) {
        const float* Asrc = (kt < 2) ? Aagg : Ax;
        int kcol = (kt & 1) * 64;

        // --- stage A (fp32 -> bf16 hi/lo), 64 rows x 64 k: 512 slots of 8
#pragma unroll
        for (int it = 0; it < 2; ++it) {
            int slot = tid + it * 256;
            int row = slot >> 3;
            int k8 = (slot & 7) * 8;
            int gr = row0 + row;
            if (gr >= M) gr = M - 1;
            const float* p = &Asrc[(size_t)gr * D + kcol + k8];
            float4 v0 = *(const float4*)p;
            float4 v1 = *(const float4*)(p + 4);
            float fv[8] = {v0.x, v0.y, v0.z, v0.w, v1.x, v1.y, v1.z, v1.w};
            union { unsigned short u[8]; uint4 q; } ph, pl;
#pragma unroll
            for (int j = 0; j < 8; ++j) {
                unsigned short h = f2bf(fv[j]);
                ph.u[j] = h;
                pl.u[j] = f2bf(fv[j] - bf2f(h));
            }
            int boff = (row << 7) + (k8 << 1);
            boff ^= (row & 7) << 4;             // st_8x16-style XOR swizzle
            *(uint4*)(AhB + boff) = ph.q;
            *(uint4*)(AlB + boff) = pl.q;
        }
        // --- stage W (pre-split bf16), 128 n x 64 k: 1024 slots of 8
#pragma unroll
        for (int it = 0; it < 4; ++it) {
            int slot = tid + it * 256;
            int n = slot >> 3;
            int k8 = (slot & 7) * 8;
            size_t gsrc = (size_t)n * 256 + kt * 64 + k8;
            uint4 h = *(const uint4*)&Whi[gsrc];
            uint4 l = *(const uint4*)&Wlo[gsrc];
            int boff = (n << 7) + (k8 << 1);
            boff ^= (n & 7) << 4;
            *(uint4*)(WhB + boff) = h;
            *(uint4*)(WlB + boff) = l;
        }
        __syncthreads();

        // --- compute: 2 k-steps of 32
#pragma unroll
        for (int ks = 0; ks < 2; ++ks) {
            int kk = ks * 32 + kg;
            bf16x8 ah[2], al[2];
#pragma unroll
            for (int f = 0; f < 2; ++f) {
                int row = wr * 32 + f * 16 + lr;
                int boff = (row << 7) + (kk << 1);
                boff ^= (row & 7) << 4;
                ah[f] = *(const bf16x8*)(AhB + boff);
                al[f] = *(const bf16x8*)(AlB + boff);
            }
            bf16x8 bh[4], bl[4];
#pragma unroll
            for (int j = 0; j < 4; ++j) {
                int n = wc * 64 + j * 16 + lr;
                int boff = (n << 7) + (kk << 1);
                boff ^= (n & 7) << 4;
                bh[j] = *(const bf16x8*)(WhB + boff);
                bl[j] = *(const bf16x8*)(WlB + boff);
            }
#pragma unroll
            for (int f = 0; f < 2; ++f)
#pragma unroll
                for (int j = 0; j < 4; ++j) {
                    acc[f][j] = __builtin_amdgcn_mfma_f32_16x16x32_bf16(ah[f], bh[j], acc[f][j], 0, 0, 0);
                    acc[f][j] = __builtin_amdgcn_mfma_f32_16x16x32_bf16(ah[f], bl[j], acc[f][j], 0, 0, 0);
                    acc[f][j] = __builtin_amdgcn_mfma_f32_16x16x32_bf16(al[f], bh[j], acc[f][j], 0, 0, 0);
                }
        }
        __syncthreads();
    }

    // --- epilogue: bias + relu (+ residual). D lane map: row=(l>>4)*4+r, col=l&15
#pragma unroll
    for (int f = 0; f < 2; ++f)
#pragma unroll
        for (int j = 0; j < 4; ++j) {
            int c = wc * 64 + j * 16 + lr;
            float b = bias[c];
#pragma unroll
            for (int r = 0; r < 4; ++r) {
                int gr = row0 + wr * 32 + f * 16 + (lane >> 4) * 4 + r;
                if (gr < M) {
                    float v = acc[f][j][r] + b;
                    v = fmaxf(v, 0.f);
                    if (resid) v += resid[(size_t)gr * D + c];
                    outp[(size_t)gr * D + c] = v;
                }
            }
        }
}

// ---------------------------------------------------------------------------
// Classifier: out[M,40] = vif @ Wc^T + bc. 64 rows/block, both operands in LDS.
// ---------------------------------------------------------------------------
__global__ __launch_bounds__(256) void classifier_kernel(const float* __restrict__ vif,
                                                         const float* __restrict__ Wc,
                                                         const float* __restrict__ bc,
                                                         float* __restrict__ outp, int M) {
    __shared__ float Vs[64][D + 4];
    __shared__ float Cs[N_CLS][D + 4];
    int tid = threadIdx.x;
    int row0 = blockIdx.x * 64;

#pragma unroll
    for (int l = 0; l < 8; ++l) {
        int slot = tid + l * 256;
        int r = slot >> 5;
        int kq = slot & 31;
        int gr = row0 + r;
        if (gr >= M) gr = M - 1;
        float4 v = *(const float4*)&vif[(size_t)gr * D + kq * 4];
        *(float4*)&Vs[r][kq * 4] = v;
    }
#pragma unroll
    for (int l = 0; l < 5; ++l) {
        int slot = tid + l * 256;
        int r = slot >> 5;
        int kq = slot & 31;
        float4 v = *(const float4*)&Wc[r * D + kq * 4];
        *(float4*)&Cs[r][kq * 4] = v;
    }
    __syncthreads();

    int r2 = tid >> 3;
    int cg = tid & 7;
    float acc[2][5] = {};
#pragma unroll 4
    for (int k4 = 0; k4 < 32; ++k4) {
        float4 a0 = *(const float4*)&Vs[r2 * 2][k4 * 4];
        float4 a1 = *(const float4*)&Vs[r2 * 2 + 1][k4 * 4];
#pragma unroll
        for (int j = 0; j < 5; ++j) {
            float4 w = *(const float4*)&Cs[cg * 5 + j][k4 * 4];
            acc[0][j] = fmaf(a0.x, w.x, fmaf(a0.y, w.y, fmaf(a0.z, w.z, fmaf(a0.w, w.w, acc[0][j]))));
            acc[1][j] = fmaf(a1.x, w.x, fmaf(a1.y, w.y, fmaf(a1.z, w.z, fmaf(a1.w, w.w, acc[1][j]))));
        }
    }
#pragma unroll
    for (int i = 0; i < 2; ++i) {
        int r = row0 + r2 * 2 + i;
        if (r >= M) continue;
#pragma unroll
        for (int j = 0; j < 5; ++j) {
            int c = cg * 5 + j;
            outp[(size_t)r * N_CLS + c] = acc[i][j] + bc[c];
        }
    }
}

// ---------------------------------------------------------------------------
extern "C" void kernel_launch(void* const* d_in, const int* in_sizes, int n_in,
                              void* d_out, int out_size, void* d_ws, size_t ws_size,
                              hipStream_t stream) {
    const float* x   = (const float*)d_in[0];
    const int*   ei  = (const int*)d_in[1];
    const float* Wl1 = (const float*)d_in[2];
    const float* bl1 = (const float*)d_in[3];
    const float* Wr1 = (const float*)d_in[4];
    const float* Wl2 = (const float*)d_in[5];
    const float* bl2 = (const float*)d_in[6];
    const float* Wr2 = (const float*)d_in[7];
    const float* Wl3 = (const float*)d_in[8];
    const float* bl3 = (const float*)d_in[9];
    const float* Wr3 = (const float*)d_in[10];
    const float* Wc  = (const float*)d_in[11];
    const float* bc  = (const float*)d_in[12];
    float* out = (float*)d_out;

    // workspace carve (256B aligned)
    char* w = (char*)d_ws;
    size_t off = 0;
    auto carve = [&](size_t bytes) -> void* {
        void* p = w + off;
        off = (off + bytes + 255) & ~(size_t)255;
        return p;
    };
    int*   cnt    = (int*)carve((size_t)N_NODES * 4);
    int*   rs     = (int*)carve((size_t)(N_NODES + 1) * 4);
    int*   cursor = (int*)carve((size_t)N_NODES * 4);
    float* dinv   = (float*)carve((size_t)N_NODES * 4);
    int*   bsum   = (int*)carve(64 * 4);
    int*   boff   = (int*)carve(64 * 4);
    int*   csr    = (int*)carve((size_t)N_EDGES * 4);
    float* aggn   = (float*)carve((size_t)N_NODES * D * 4);
    float* bufA   = (float*)carve((size_t)N_NODES * D * 4);
    float* bufB   = (float*)carve((size_t)N_NODES * D * 4);
    unsigned short* w1h = (unsigned short*)carve(128 * 256 * 2);
    unsigned short* w1l = (unsigned short*)carve(128 * 256 * 2);
    unsigned short* w2h = (unsigned short*)carve(128 * 256 * 2);
    unsigned short* w2l = (unsigned short*)carve(128 * 256 * 2);
    unsigned short* w3h = (unsigned short*)carve(128 * 256 * 2);
    unsigned short* w3l = (unsigned short*)carve(128 * 256 * 2);
    (void)ws_size;

    const int NBLK_SCAN = (N_NODES + 1023) / 1024;           // 49
    const int GRID_E = (N_EDGES + 255) / 256;                // 2344
    const int GRID_N = (N_NODES + 255) / 256;                // 196
    const int GRID_AGG = (N_NODES + 3) / 4;                  // 12500
    const int GRID_GEMM = (N_NODES + 63) / 64;               // 782

    // CSR build + weight split (independent work up front)
    hipMemsetAsync(cnt, 0, (size_t)N_NODES * 4, stream);
    hipLaunchKernelGGL(hist_kernel, dim3(GRID_E), dim3(256), 0, stream, ei, cnt);
    hipLaunchKernelGGL(split_w_kernel, dim3(128), dim3(256), 0, stream, Wl1, Wr1, w1h, w1l);
    hipLaunchKernelGGL(split_w_kernel, dim3(128), dim3(256), 0, stream, Wl2, Wr2, w2h, w2l);
    hipLaunchKernelGGL(split_w_kernel, dim3(128), dim3(256), 0, stream, Wl3, Wr3, w3h, w3l);
    hipLaunchKernelGGL(scan_block_kernel, dim3(NBLK_SCAN), dim3(1024), 0, stream, cnt, rs, bsum, N_NODES);
    hipLaunchKernelGGL(scan_sums_kernel, dim3(1), dim3(64), 0, stream, bsum, boff, NBLK_SCAN);
    hipLaunchKernelGGL(finalize_kernel, dim3(GRID_N), dim3(256), 0, stream, cnt, rs, cursor, dinv, boff);
    hipLaunchKernelGGL(scatter_kernel, dim3(GRID_E), dim3(256), 0, stream, ei, cursor, csr);

    // Layer 1
    hipLaunchKernelGGL(agg_kernel, dim3(GRID_AGG), dim3(256), 0, stream, x, rs, csr, dinv, aggn);
    hipLaunchKernelGGL(gemm_mfma_kernel, dim3(GRID_GEMM), dim3(256), 0, stream,
                       aggn, x, w1h, w1l, bl1, (const float*)nullptr, bufA, N_NODES);
    // Layer 2
    hipLaunchKernelGGL(agg_kernel, dim3(GRID_AGG), dim3(256), 0, stream, bufA, rs, csr, dinv, aggn);
    hipLaunchKernelGGL(gemm_mfma_kernel, dim3(GRID_GEMM), dim3(256), 0, stream,
                       aggn, bufA, w2h, w2l, bl2, (const float*)nullptr, bufB, N_NODES);
    // Layer 3 + residual -> vif (bufA)
    hipLaunchKernelGGL(agg_kernel, dim3(GRID_AGG), dim3(256), 0, stream, bufB, rs, csr, dinv, aggn);
    hipLaunchKernelGGL(gemm_mfma_kernel, dim3(GRID_GEMM), dim3(256), 0, stream,
                       aggn, bufB, w3h, w3l, bl3, bufB, bufA, N_NODES);
    // Classifier
    hipLaunchKernelGGL(classifier_kernel, dim3(GRID_GEMM), dim3(256), 0, stream,
                       bufA, Wc, bc, out, N_NODES);
}

// Round 3
// 385.544 us; speedup vs baseline: 1.2577x; 1.0140x over previous
//
#include <hip/hip_runtime.h>
#include <hip/hip_bf16.h>

// Problem constants (match reference)
constexpr int N_NODES = 50000;
constexpr int N_EDGES = 600000;
constexpr int D       = 128;   // IN_DIM == FEAT
constexpr int N_CLS   = 40;

using bf16x8 = __attribute__((ext_vector_type(8))) short;   // 8 bf16 = 4 VGPR
using f32x4  = __attribute__((ext_vector_type(4))) float;   // MFMA C/D

__device__ inline unsigned short f2bf(float f) {
    __hip_bfloat16 h = __float2bfloat16(f);
    return __builtin_bit_cast(unsigned short, h);
}
__device__ inline float bf2f(unsigned short u) {
    __hip_bfloat16 h = __builtin_bit_cast(__hip_bfloat16, u);
    return __bfloat162float(h);
}

// ---------------------------------------------------------------------------
// CSR build: histogram -> block scan -> sum scan -> finalize -> scatter
// ---------------------------------------------------------------------------

__global__ void hist_kernel(const int* __restrict__ ei, int* __restrict__ cnt) {
    int e = blockIdx.x * 256 + threadIdx.x;
    if (e < N_EDGES) atomicAdd(&cnt[ei[N_EDGES + e]], 1);
}

__global__ __launch_bounds__(1024) void scan_block_kernel(const int* __restrict__ cnt,
                                                          int* __restrict__ rs,
                                                          int* __restrict__ bsum, int n) {
    __shared__ int t[1024];
    int tid = threadIdx.x;
    int gid = blockIdx.x * 1024 + tid;
    int v = (gid < n) ? cnt[gid] : 0;
    t[tid] = v;
    __syncthreads();
    for (int off = 1; off < 1024; off <<= 1) {
        int u = (tid >= off) ? t[tid - off] : 0;
        __syncthreads();
        t[tid] += u;
        __syncthreads();
    }
    if (gid < n) rs[gid] = t[tid] - v;          // exclusive within block
    if (tid == 1023) bsum[blockIdx.x] = t[1023];
}

__global__ void scan_sums_kernel(const int* __restrict__ bsum, int* __restrict__ boff, int nblk) {
    __shared__ int t[64];
    int tid = threadIdx.x;
    int v = (tid < nblk) ? bsum[tid] : 0;
    t[tid] = v;
    __syncthreads();
    for (int off = 1; off < 64; off <<= 1) {
        int u = (tid >= off) ? t[tid - off] : 0;
        __syncthreads();
        t[tid] += u;
        __syncthreads();
    }
    if (tid < nblk) boff[tid] = t[tid] - v;     // exclusive
}

__global__ void finalize_kernel(const int* __restrict__ cnt, int* __restrict__ rs,
                                int* __restrict__ cursor, float* __restrict__ dinv,
                                const int* __restrict__ boff) {
    int i = blockIdx.x * 256 + threadIdx.x;
    if (i < N_NODES) {
        int v = rs[i] + boff[i >> 10];
        rs[i] = v;
        cursor[i] = v;
        dinv[i] = 1.0f / fmaxf((float)cnt[i], 1.0f);
        if (i == 0) rs[N_NODES] = N_EDGES;
    }
}

__global__ void scatter_kernel(const int* __restrict__ ei, int* __restrict__ cursor,
                               int* __restrict__ csr) {
    int e = blockIdx.x * 256 + threadIdx.x;
    if (e < N_EDGES) {
        int d = ei[N_EDGES + e];
        int p = atomicAdd(&cursor[d], 1);
        csr[p] = ei[e];
    }
}

// ---------------------------------------------------------------------------
// Weight split: Wcat_hi/lo[n][256] bf16 = [ Wl[n][0..127] | Wr[n][0..127] ]
// ---------------------------------------------------------------------------
__global__ void split_w_kernel(const float* __restrict__ Wl, const float* __restrict__ Wr,
                               unsigned short* __restrict__ hi, unsigned short* __restrict__ lo) {
    int idx = blockIdx.x * 256 + threadIdx.x;   // 0..32767
    int n = idx >> 8, k = idx & 255;
    float v = (k < 128) ? Wl[n * 128 + k] : Wr[n * 128 + (k - 128)];
    unsigned short h = f2bf(v);
    hi[idx] = h;
    lo[idx] = f2bf(v - bf2f(h));
}

// ---------------------------------------------------------------------------
// Mean aggregation, MLP-optimized: one wave per node. Lane loads float4 so
// 32 lanes cover one 512B row => each instruction gathers TWO rows (1KB).
// Unroll 4 pairs => 8 edges in flight per wave. Edge indices loaded coalesced
// per 64-chunk and broadcast via shfl (ds pipe). Cross-half reduce at end.
// ---------------------------------------------------------------------------
__global__ __launch_bounds__(256) void agg_kernel(const float* __restrict__ feat,
                                                  const int* __restrict__ rs,
                                                  const int* __restrict__ csr,
                                                  const float* __restrict__ dinv,
                                                  float* __restrict__ aggn) {
    int wave = threadIdx.x >> 6;
    int lane = threadIdx.x & 63;
    int node = blockIdx.x * 4 + wave;
    if (node >= N_NODES) return;
    int e0 = rs[node], e1 = rs[node + 1];
    int half = lane >> 5;        // 0: even edges, 1: odd edges
    int fl = lane & 31;          // feature quad: floats fl*4 .. fl*4+3
    float ax = 0.f, ay = 0.f, az = 0.f, aw = 0.f;

    for (int base = e0; base < e1; base += 64) {
        int cnt = min(64, e1 - base);
        int idxv = (lane < cnt) ? csr[base + lane] : 0;
        int cnt2 = cnt & ~1;
        int j = 0;
        // 4 pairs (8 edges) in flight
        for (; j + 8 <= cnt2; j += 8) {
            int s0 = __shfl(idxv, j + half);
            int s1 = __shfl(idxv, j + 2 + half);
            int s2 = __shfl(idxv, j + 4 + half);
            int s3 = __shfl(idxv, j + 6 + half);
            float4 v0 = *(const float4*)&feat[(size_t)s0 * D + fl * 4];
            float4 v1 = *(const float4*)&feat[(size_t)s1 * D + fl * 4];
            float4 v2 = *(const float4*)&feat[(size_t)s2 * D + fl * 4];
            float4 v3 = *(const float4*)&feat[(size_t)s3 * D + fl * 4];
            ax += v0.x + v1.x + v2.x + v3.x;
            ay += v0.y + v1.y + v2.y + v3.y;
            az += v0.z + v1.z + v2.z + v3.z;
            aw += v0.w + v1.w + v2.w + v3.w;
        }
        for (; j < cnt2; j += 2) {
            int s = __shfl(idxv, j + half);
            float4 v = *(const float4*)&feat[(size_t)s * D + fl * 4];
            ax += v.x; ay += v.y; az += v.z; aw += v.w;
        }
        if (j < cnt) {                       // odd tail: half 0 only
            int s = __shfl(idxv, j);
            if (half == 0) {
                float4 v = *(const float4*)&feat[(size_t)s * D + fl * 4];
                ax += v.x; ay += v.y; az += v.z; aw += v.w;
            }
        }
    }
    // cross-half reduce (even-edge partial + odd-edge partial)
    ax += __shfl(ax, lane ^ 32);
    ay += __shfl(ay, lane ^ 32);
    az += __shfl(az, lane ^ 32);
    aw += __shfl(aw, lane ^ 32);
    if (half == 0) {
        float di = dinv[node];
        float4 o; o.x = ax * di; o.y = ay * di; o.z = az * di; o.w = aw * di;
        *(float4*)&aggn[(size_t)node * D + fl * 4] = o;
    }
}

// ---------------------------------------------------------------------------
// Split-bf16 MFMA GEMM: out = relu([Aagg|Ax] @ Wcat^T + bias) [+ resid]
// (unchanged from R1 — per-dispatch counters keep the agg A/B clean)
// ---------------------------------------------------------------------------
__global__ __launch_bounds__(256) void gemm_mfma_kernel(const float* __restrict__ Aagg,
                                                        const float* __restrict__ Ax,
                                                        const unsigned short* __restrict__ Whi,
                                                        const unsigned short* __restrict__ Wlo,
                                                        const float* __restrict__ bias,
                                                        const float* __restrict__ resid,
                                                        float* __restrict__ outp, int M) {
    __shared__ __align__(16) unsigned short AhS[64 * 64];
    __shared__ __align__(16) unsigned short AlS[64 * 64];
    __shared__ __align__(16) unsigned short WhS[128 * 64];
    __shared__ __align__(16) unsigned short WlS[128 * 64];
    char* AhB = (char*)AhS;
    char* AlB = (char*)AlS;
    char* WhB = (char*)WhS;
    char* WlB = (char*)WlS;

    int tid = threadIdx.x;
    int lane = tid & 63;
    int wid = tid >> 6;
    int wr = wid >> 1;          // 0..1: row half (32 rows)
    int wc = wid & 1;           // 0..1: col half (64 cols)
    int lr = lane & 15;
    int kg = (lane >> 4) * 8;
    int row0 = blockIdx.x * 64;

    f32x4 acc[2][4];
#pragma unroll
    for (int f = 0; f < 2; ++f)
#pragma unroll
        for (int j = 0; j < 4; ++j) acc[f][j] = (f32x4){0.f, 0.f, 0.f, 0.f};

    for (int kt = 0; kt < 4; ++kt) {
        const float* Asrc = (kt < 2) ? Aagg : Ax;
        int kcol = (kt & 1) * 64;

        // --- stage A (fp32 -> bf16 hi/lo), 64 rows x 64 k
#pragma unroll
        for (int it = 0; it < 2; ++it) {
            int slot = tid + it * 256;
            int row = slot >> 3;
            int k8 = (slot & 7) * 8;
            int gr = row0 + row;
            if (gr >= M) gr = M - 1;
            const float* p = &Asrc[(size_t)gr * D + kcol + k8];
            float4 v0 = *(const float4*)p;
            float4 v1 = *(const float4*)(p + 4);
            float fv[8] = {v0.x, v0.y, v0.z, v0.w, v1.x, v1.y, v1.z, v1.w};
            union { unsigned short u[8]; uint4 q; } ph, pl;
#pragma unroll
            for (int j = 0; j < 8; ++j) {
                unsigned short h = f2bf(fv[j]);
                ph.u[j] = h;
                pl.u[j] = f2bf(fv[j] - bf2f(h));
            }
            int boff = (row << 7) + (k8 << 1);
            boff ^= (row & 7) << 4;
            *(uint4*)(AhB + boff) = ph.q;
            *(uint4*)(AlB + boff) = pl.q;
        }
        // --- stage W (pre-split bf16), 128 n x 64 k
#pragma unroll
        for (int it = 0; it < 4; ++it) {
            int slot = tid + it * 256;
            int n = slot >> 3;
            int k8 = (slot & 7) * 8;
            size_t gsrc = (size_t)n * 256 + kt * 64 + k8;
            uint4 h = *(const uint4*)&Whi[gsrc];
            uint4 l = *(const uint4*)&Wlo[gsrc];
            int boff = (n << 7) + (k8 << 1);
            boff ^= (n & 7) << 4;
            *(uint4*)(WhB + boff) = h;
            *(uint4*)(WlB + boff) = l;
        }
        __syncthreads();

#pragma unroll
        for (int ks = 0; ks < 2; ++ks) {
            int kk = ks * 32 + kg;
            bf16x8 ah[2], al[2];
#pragma unroll
            for (int f = 0; f < 2; ++f) {
                int row = wr * 32 + f * 16 + lr;
                int boff = (row << 7) + (kk << 1);
                boff ^= (row & 7) << 4;
                ah[f] = *(const bf16x8*)(AhB + boff);
                al[f] = *(const bf16x8*)(AlB + boff);
            }
            bf16x8 bh[4], bl[4];
#pragma unroll
            for (int j = 0; j < 4; ++j) {
                int n = wc * 64 + j * 16 + lr;
                int boff = (n << 7) + (kk << 1);
                boff ^= (n & 7) << 4;
                bh[j] = *(const bf16x8*)(WhB + boff);
                bl[j] = *(const bf16x8*)(WlB + boff);
            }
#pragma unroll
            for (int f = 0; f < 2; ++f)
#pragma unroll
                for (int j = 0; j < 4; ++j) {
                    acc[f][j] = __builtin_amdgcn_mfma_f32_16x16x32_bf16(ah[f], bh[j], acc[f][j], 0, 0, 0);
                    acc[f][j] = __builtin_amdgcn_mfma_f32_16x16x32_bf16(ah[f], bl[j], acc[f][j], 0, 0, 0);
                    acc[f][j] = __builtin_amdgcn_mfma_f32_16x16x32_bf16(al[f], bh[j], acc[f][j], 0, 0, 0);
                }
        }
        __syncthreads();
    }

    // --- epilogue: bias + relu (+ residual). D map: row=(l>>4)*4+r, col=l&15
#pragma unroll
    for (int f = 0; f < 2; ++f)
#pragma unroll
        for (int j = 0; j < 4; ++j) {
            int c = wc * 64 + j * 16 + lr;
            float b = bias[c];
#pragma unroll
            for (int r = 0; r < 4; ++r) {
                int gr = row0 + wr * 32 + f * 16 + (lane >> 4) * 4 + r;
                if (gr < M) {
                    float v = acc[f][j][r] + b;
                    v = fmaxf(v, 0.f);
                    if (resid) v += resid[(size_t)gr * D + c];
                    outp[(size_t)gr * D + c] = v;
                }
            }
        }
}

// ---------------------------------------------------------------------------
// Classifier: out[M,40] = vif @ Wc^T + bc.
// ---------------------------------------------------------------------------
__global__ __launch_bounds__(256) void classifier_kernel(const float* __restrict__ vif,
                                                         const float* __restrict__ Wc,
                                                         const float* __restrict__ bc,
                                                         float* __restrict__ outp, int M) {
    __shared__ float Vs[64][D + 4];
    __shared__ float Cs[N_CLS][D + 4];
    int tid = threadIdx.x;
    int row0 = blockIdx.x * 64;

#pragma unroll
    for (int l = 0; l < 8; ++l) {
        int slot = tid + l * 256;
        int r = slot >> 5;
        int kq = slot & 31;
        int gr = row0 + r;
        if (gr >= M) gr = M - 1;
        float4 v = *(const float4*)&vif[(size_t)gr * D + kq * 4];
        *(float4*)&Vs[r][kq * 4] = v;
    }
#pragma unroll
    for (int l = 0; l < 5; ++l) {
        int slot = tid + l * 256;
        int r = slot >> 5;
        int kq = slot & 31;
        float4 v = *(const float4*)&Wc[r * D + kq * 4];
        *(float4*)&Cs[r][kq * 4] = v;
    }
    __syncthreads();

    int r2 = tid >> 3;
    int cg = tid & 7;
    float acc[2][5] = {};
#pragma unroll 4
    for (int k4 = 0; k4 < 32; ++k4) {
        float4 a0 = *(const float4*)&Vs[r2 * 2][k4 * 4];
        float4 a1 = *(const float4*)&Vs[r2 * 2 + 1][k4 * 4];
#pragma unroll
        for (int j = 0; j < 5; ++j) {
            float4 w = *(const float4*)&Cs[cg * 5 + j][k4 * 4];
            acc[0][j] = fmaf(a0.x, w.x, fmaf(a0.y, w.y, fmaf(a0.z, w.z, fmaf(a0.w, w.w, acc[0][j]))));
            acc[1][j] = fmaf(a1.x, w.x, fmaf(a1.y, w.y, fmaf(a1.z, w.z, fmaf(a1.w, w.w, acc[1][j]))));
        }
    }
#pragma unroll
    for (int i = 0; i < 2; ++i) {
        int r = row0 + r2 * 2 + i;
        if (r >= M) continue;
#pragma unroll
        for (int j = 0; j < 5; ++j) {
            int c = cg * 5 + j;
            outp[(size_t)r * N_CLS + c] = acc[i][j] + bc[c];
        }
    }
}

// ---------------------------------------------------------------------------
extern "C" void kernel_launch(void* const* d_in, const int* in_sizes, int n_in,
                              void* d_out, int out_size, void* d_ws, size_t ws_size,
                              hipStream_t stream) {
    const float* x   = (const float*)d_in[0];
    const int*   ei  = (const int*)d_in[1];
    const float* Wl1 = (const float*)d_in[2];
    const float* bl1 = (const float*)d_in[3];
    const float* Wr1 = (const float*)d_in[4];
    const float* Wl2 = (const float*)d_in[5];
    const float* bl2 = (const float*)d_in[6];
    const float* Wr2 = (const float*)d_in[7];
    const float* Wl3 = (const float*)d_in[8];
    const float* bl3 = (const float*)d_in[9];
    const float* Wr3 = (const float*)d_in[10];
    const float* Wc  = (const float*)d_in[11];
    const float* bc  = (const float*)d_in[12];
    float* out = (float*)d_out;

    // workspace carve (256B aligned)
    char* w = (char*)d_ws;
    size_t off = 0;
    auto carve = [&](size_t bytes) -> void* {
        void* p = w + off;
        off = (off + bytes + 255) & ~(size_t)255;
        return p;
    };
    int*   cnt    = (int*)carve((size_t)N_NODES * 4);
    int*   rs     = (int*)carve((size_t)(N_NODES + 1) * 4);
    int*   cursor = (int*)carve((size_t)N_NODES * 4);
    float* dinv   = (float*)carve((size_t)N_NODES * 4);
    int*   bsum   = (int*)carve(64 * 4);
    int*   boff   = (int*)carve(64 * 4);
    int*   csr    = (int*)carve((size_t)N_EDGES * 4);
    float* aggn   = (float*)carve((size_t)N_NODES * D * 4);
    float* bufA   = (float*)carve((size_t)N_NODES * D * 4);
    float* bufB   = (float*)carve((size_t)N_NODES * D * 4);
    unsigned short* w1h = (unsigned short*)carve(128 * 256 * 2);
    unsigned short* w1l = (unsigned short*)carve(128 * 256 * 2);
    unsigned short* w2h = (unsigned short*)carve(128 * 256 * 2);
    unsigned short* w2l = (unsigned short*)carve(128 * 256 * 2);
    unsigned short* w3h = (unsigned short*)carve(128 * 256 * 2);
    unsigned short* w3l = (unsigned short*)carve(128 * 256 * 2);
    (void)ws_size;

    const int NBLK_SCAN = (N_NODES + 1023) / 1024;           // 49
    const int GRID_E = (N_EDGES + 255) / 256;                // 2344
    const int GRID_N = (N_NODES + 255) / 256;                // 196
    const int GRID_AGG = (N_NODES + 3) / 4;                  // 12500
    const int GRID_GEMM = (N_NODES + 63) / 64;               // 782

    // CSR build + weight split
    hipMemsetAsync(cnt, 0, (size_t)N_NODES * 4, stream);
    hipLaunchKernelGGL(hist_kernel, dim3(GRID_E), dim3(256), 0, stream, ei, cnt);
    hipLaunchKernelGGL(split_w_kernel, dim3(128), dim3(256), 0, stream, Wl1, Wr1, w1h, w1l);
    hipLaunchKernelGGL(split_w_kernel, dim3(128), dim3(256), 0, stream, Wl2, Wr2, w2h, w2l);
    hipLaunchKernelGGL(split_w_kernel, dim3(128), dim3(256), 0, stream, Wl3, Wr3, w3h, w3l);
    hipLaunchKernelGGL(scan_block_kernel, dim3(NBLK_SCAN), dim3(1024), 0, stream, cnt, rs, bsum, N_NODES);
    hipLaunchKernelGGL(scan_sums_kernel, dim3(1), dim3(64), 0, stream, bsum, boff, NBLK_SCAN);
    hipLaunchKernelGGL(finalize_kernel, dim3(GRID_N), dim3(256), 0, stream, cnt, rs, cursor, dinv, boff);
    hipLaunchKernelGGL(scatter_kernel, dim3(GRID_E), dim3(256), 0, stream, ei, cursor, csr);

    // Layer 1
    hipLaunchKernelGGL(agg_kernel, dim3(GRID_AGG), dim3(256), 0, stream, x, rs, csr, dinv, aggn);
    hipLaunchKernelGGL(gemm_mfma_kernel, dim3(GRID_GEMM), dim3(256), 0, stream,
                       aggn, x, w1h, w1l, bl1, (const float*)nullptr, bufA, N_NODES);
    // Layer 2
    hipLaunchKernelGGL(agg_kernel, dim3(GRID_AGG), dim3(256), 0, stream, bufA, rs, csr, dinv, aggn);
    hipLaunchKernelGGL(gemm_mfma_kernel, dim3(GRID_GEMM), dim3(256), 0, stream,
                       aggn, bufA, w2h, w2l, bl2, (const float*)nullptr, bufB, N_NODES);
    // Layer 3 + residual -> vif (bufA)
    hipLaunchKernelGGL(agg_kernel, dim3(GRID_AGG), dim3(256), 0, stream, bufB, rs, csr, dinv, aggn);
    hipLaunchKernelGGL(gemm_mfma_kernel, dim3(GRID_GEMM), dim3(256), 0, stream,
                       aggn, bufB, w3h, w3l, bl3, bufB, bufA, N_NODES);
    // Classifier
    hipLaunchKernelGGL(classifier_kernel, dim3(GRID_GEMM), dim3(256), 0, stream,
                       bufA, Wc, bc, out, N_NODES);
}

// Round 6
// 360.682 us; speedup vs baseline: 1.3444x; 1.0689x over previous
//
#include <hip/hip_runtime.h>
#include <hip/hip_bf16.h>

// Problem constants (match reference)
constexpr int N_NODES = 50000;
constexpr int N_EDGES = 600000;
constexpr int D       = 128;   // IN_DIM == FEAT
constexpr int N_CLS   = 40;

using bf16x8 = __attribute__((ext_vector_type(8))) short;   // 8 bf16 = 4 VGPR
using f32x4  = __attribute__((ext_vector_type(4))) float;   // MFMA C/D

__device__ inline unsigned short f2bf(float f) {
    __hip_bfloat16 h = __float2bfloat16(f);
    return __builtin_bit_cast(unsigned short, h);
}
__device__ inline float bf2f(unsigned short u) {
    __hip_bfloat16 h = __builtin_bit_cast(__hip_bfloat16, u);
    return __bfloat162float(h);
}

// ---------------------------------------------------------------------------
// CSR build: histogram -> block scan -> sum scan -> finalize -> scatter
// ---------------------------------------------------------------------------

__global__ void hist_kernel(const int* __restrict__ ei, int* __restrict__ cnt) {
    int e = blockIdx.x * 256 + threadIdx.x;
    if (e < N_EDGES) atomicAdd(&cnt[ei[N_EDGES + e]], 1);
}

__global__ __launch_bounds__(1024) void scan_block_kernel(const int* __restrict__ cnt,
                                                          int* __restrict__ rs,
                                                          int* __restrict__ bsum, int n) {
    __shared__ int t[1024];
    int tid = threadIdx.x;
    int gid = blockIdx.x * 1024 + tid;
    int v = (gid < n) ? cnt[gid] : 0;
    t[tid] = v;
    __syncthreads();
    for (int off = 1; off < 1024; off <<= 1) {
        int u = (tid >= off) ? t[tid - off] : 0;
        __syncthreads();
        t[tid] += u;
        __syncthreads();
    }
    if (gid < n) rs[gid] = t[tid] - v;          // exclusive within block
    if (tid == 1023) bsum[blockIdx.x] = t[1023];
}

__global__ void scan_sums_kernel(const int* __restrict__ bsum, int* __restrict__ boff, int nblk) {
    __shared__ int t[64];
    int tid = threadIdx.x;
    int v = (tid < nblk) ? bsum[tid] : 0;
    t[tid] = v;
    __syncthreads();
    for (int off = 1; off < 64; off <<= 1) {
        int u = (tid >= off) ? t[tid - off] : 0;
        __syncthreads();
        t[tid] += u;
        __syncthreads();
    }
    if (tid < nblk) boff[tid] = t[tid] - v;     // exclusive
}

__global__ void finalize_kernel(const int* __restrict__ cnt, int* __restrict__ rs,
                                int* __restrict__ cursor, float* __restrict__ dinv,
                                const int* __restrict__ boff) {
    int i = blockIdx.x * 256 + threadIdx.x;
    if (i < N_NODES) {
        int v = rs[i] + boff[i >> 10];
        rs[i] = v;
        cursor[i] = v;
        dinv[i] = 1.0f / fmaxf((float)cnt[i], 1.0f);
        if (i == 0) rs[N_NODES] = N_EDGES;
    }
}

__global__ void scatter_kernel(const int* __restrict__ ei, int* __restrict__ cursor,
                               int* __restrict__ csr) {
    int e = blockIdx.x * 256 + threadIdx.x;
    if (e < N_EDGES) {
        int d = ei[N_EDGES + e];
        int p = atomicAdd(&cursor[d], 1);
        csr[p] = ei[e];
    }
}

// ---------------------------------------------------------------------------
// Weight split, all 3 layers in one launch:
// w123h/l[layer][n][256] bf16 = split of [ Wl[n][:] | Wr[n][:] ]
// ---------------------------------------------------------------------------
__global__ void split_w3_kernel(const float* __restrict__ Wl1, const float* __restrict__ Wr1,
                                const float* __restrict__ Wl2, const float* __restrict__ Wr2,
                                const float* __restrict__ Wl3, const float* __restrict__ Wr3,
                                unsigned short* __restrict__ hi, unsigned short* __restrict__ lo) {
    int layer = blockIdx.x >> 7;                       // 0..2
    int idx = (blockIdx.x & 127) * 256 + threadIdx.x;  // 0..32767
    int n = idx >> 8, k = idx & 255;
    const float* Wl = (layer == 0) ? Wl1 : (layer == 1) ? Wl2 : Wl3;
    const float* Wr = (layer == 0) ? Wr1 : (layer == 1) ? Wr2 : Wr3;
    float v = (k < 128) ? Wl[n * 128 + k] : Wr[n * 128 + (k - 128)];
    unsigned short h = f2bf(v);
    size_t o = (size_t)layer * 32768 + idx;
    hi[o] = h;
    lo[o] = f2bf(v - bf2f(h));
}

// Classifier weight split: wc_h/l[48][128] bf16 (rows 40..47 zero-padded)
__global__ void split_wc_kernel(const float* __restrict__ Wc,
                                unsigned short* __restrict__ hi, unsigned short* __restrict__ lo) {
    int idx = blockIdx.x * 256 + threadIdx.x;   // 0..6143
    int n = idx >> 7, k = idx & 127;
    float v = (n < N_CLS) ? Wc[n * 128 + k] : 0.f;
    unsigned short h = f2bf(v);
    hi[idx] = h;
    lo[idx] = f2bf(v - bf2f(h));
}

// ---------------------------------------------------------------------------
// Mean aggregation (R3-proven, fp32): one wave per node. Lane loads float4 so
// 32 lanes cover one 512B row => each instruction gathers TWO rows (1KB).
// Unroll 4 pairs => 8 edges in flight. Cross-half shfl reduce at end.
// ---------------------------------------------------------------------------
__global__ __launch_bounds__(256) void agg_kernel(const float* __restrict__ feat,
                                                  const int* __restrict__ rs,
                                                  const int* __restrict__ csr,
                                                  const float* __restrict__ dinv,
                                                  float* __restrict__ aggn) {
    int wave = threadIdx.x >> 6;
    int lane = threadIdx.x & 63;
    int node = blockIdx.x * 4 + wave;
    if (node >= N_NODES) return;
    int e0 = rs[node], e1 = rs[node + 1];
    int half = lane >> 5;        // 0: even edges, 1: odd edges
    int fl = lane & 31;          // feature quad: floats fl*4 .. fl*4+3
    float ax = 0.f, ay = 0.f, az = 0.f, aw = 0.f;

    for (int base = e0; base < e1; base += 64) {
        int cnt = min(64, e1 - base);
        int idxv = (lane < cnt) ? csr[base + lane] : 0;
        int cnt2 = cnt & ~1;
        int j = 0;
        for (; j + 8 <= cnt2; j += 8) {
            int s0 = __shfl(idxv, j + half);
            int s1 = __shfl(idxv, j + 2 + half);
            int s2 = __shfl(idxv, j + 4 + half);
            int s3 = __shfl(idxv, j + 6 + half);
            float4 v0 = *(const float4*)&feat[(size_t)s0 * D + fl * 4];
            float4 v1 = *(const float4*)&feat[(size_t)s1 * D + fl * 4];
            float4 v2 = *(const float4*)&feat[(size_t)s2 * D + fl * 4];
            float4 v3 = *(const float4*)&feat[(size_t)s3 * D + fl * 4];
            ax += v0.x + v1.x + v2.x + v3.x;
            ay += v0.y + v1.y + v2.y + v3.y;
            az += v0.z + v1.z + v2.z + v3.z;
            aw += v0.w + v1.w + v2.w + v3.w;
        }
        for (; j < cnt2; j += 2) {
            int s = __shfl(idxv, j + half);
            float4 v = *(const float4*)&feat[(size_t)s * D + fl * 4];
            ax += v.x; ay += v.y; az += v.z; aw += v.w;
        }
        if (j < cnt) {                       // odd tail: half 0 only
            int s = __shfl(idxv, j);
            if (half == 0) {
                float4 v = *(const float4*)&feat[(size_t)s * D + fl * 4];
                ax += v.x; ay += v.y; az += v.z; aw += v.w;
            }
        }
    }
    ax += __shfl(ax, lane ^ 32);
    ay += __shfl(ay, lane ^ 32);
    az += __shfl(az, lane ^ 32);
    aw += __shfl(aw, lane ^ 32);
    if (half == 0) {
        float di = dinv[node];
        float4 o; o.x = ax * di; o.y = ay * di; o.z = az * di; o.w = aw * di;
        *(float4*)&aggn[(size_t)node * D + fl * 4] = o;
    }
}

// ---------------------------------------------------------------------------
// Split-bf16 MFMA GEMM (layers 1-2): out = relu([Aagg|Ax] @ Wcat^T + bias)
// ---------------------------------------------------------------------------
__global__ __launch_bounds__(256) void gemm_mfma_kernel(const float* __restrict__ Aagg,
                                                        const float* __restrict__ Ax,
                                                        const unsigned short* __restrict__ Whi,
                                                        const unsigned short* __restrict__ Wlo,
                                                        const float* __restrict__ bias,
                                                        float* __restrict__ outp, int M) {
    __shared__ __align__(16) unsigned short AhS[64 * 64];
    __shared__ __align__(16) unsigned short AlS[64 * 64];
    __shared__ __align__(16) unsigned short WhS[128 * 64];
    __shared__ __align__(16) unsigned short WlS[128 * 64];
    char* AhB = (char*)AhS;
    char* AlB = (char*)AlS;
    char* WhB = (char*)WhS;
    char* WlB = (char*)WlS;

    int tid = threadIdx.x;
    int lane = tid & 63;
    int wid = tid >> 6;
    int wr = wid >> 1;          // row half (32 rows)
    int wc = wid & 1;           // col half (64 cols)
    int lr = lane & 15;
    int kg = (lane >> 4) * 8;
    int row0 = blockIdx.x * 64;

    f32x4 acc[2][4];
#pragma unroll
    for (int f = 0; f < 2; ++f)
#pragma unroll
        for (int j = 0; j < 4; ++j) acc[f][j] = (f32x4){0.f, 0.f, 0.f, 0.f};

    for (int kt = 0; kt < 4; ++kt) {
        const float* Asrc = (kt < 2) ? Aagg : Ax;
        int kcol = (kt & 1) * 64;

#pragma unroll
        for (int it = 0; it < 2; ++it) {
            int slot = tid + it * 256;
            int row = slot >> 3;
            int k8 = (slot & 7) * 8;
            int gr = row0 + row;
            if (gr >= M) gr = M - 1;
            const float* p = &Asrc[(size_t)gr * D + kcol + k8];
            float4 v0 = *(const float4*)p;
            float4 v1 = *(const float4*)(p + 4);
            float fv[8] = {v0.x, v0.y, v0.z, v0.w, v1.x, v1.y, v1.z, v1.w};
            union { unsigned short u[8]; uint4 q; } ph, pl;
#pragma unroll
            for (int j = 0; j < 8; ++j) {
                unsigned short h = f2bf(fv[j]);
                ph.u[j] = h;
                pl.u[j] = f2bf(fv[j] - bf2f(h));
            }
            int boff = (row << 7) + (k8 << 1);
            boff ^= (row & 7) << 4;
            *(uint4*)(AhB + boff) = ph.q;
            *(uint4*)(AlB + boff) = pl.q;
        }
#pragma unroll
        for (int it = 0; it < 4; ++it) {
            int slot = tid + it * 256;
            int n = slot >> 3;
            int k8 = (slot & 7) * 8;
            size_t gsrc = (size_t)n * 256 + kt * 64 + k8;
            uint4 h = *(const uint4*)&Whi[gsrc];
            uint4 l = *(const uint4*)&Wlo[gsrc];
            int boff = (n << 7) + (k8 << 1);
            boff ^= (n & 7) << 4;
            *(uint4*)(WhB + boff) = h;
            *(uint4*)(WlB + boff) = l;
        }
        __syncthreads();

#pragma unroll
        for (int ks = 0; ks < 2; ++ks) {
            int kk = ks * 32 + kg;
            bf16x8 ah[2], al[2];
#pragma unroll
            for (int f = 0; f < 2; ++f) {
                int row = wr * 32 + f * 16 + lr;
                int boff = (row << 7) + (kk << 1);
                boff ^= (row & 7) << 4;
                ah[f] = *(const bf16x8*)(AhB + boff);
                al[f] = *(const bf16x8*)(AlB + boff);
            }
            bf16x8 bh[4], bl[4];
#pragma unroll
            for (int j = 0; j < 4; ++j) {
                int n = wc * 64 + j * 16 + lr;
                int boff = (n << 7) + (kk << 1);
                boff ^= (n & 7) << 4;
                bh[j] = *(const bf16x8*)(WhB + boff);
                bl[j] = *(const bf16x8*)(WlB + boff);
            }
#pragma unroll
            for (int f = 0; f < 2; ++f)
#pragma unroll
                for (int j = 0; j < 4; ++j) {
                    acc[f][j] = __builtin_amdgcn_mfma_f32_16x16x32_bf16(ah[f], bh[j], acc[f][j], 0, 0, 0);
                    acc[f][j] = __builtin_amdgcn_mfma_f32_16x16x32_bf16(ah[f], bl[j], acc[f][j], 0, 0, 0);
                    acc[f][j] = __builtin_amdgcn_mfma_f32_16x16x32_bf16(al[f], bh[j], acc[f][j], 0, 0, 0);
                }
        }
        __syncthreads();
    }

    // epilogue: bias + relu. D map: row=(l>>4)*4+r, col=l&15
#pragma unroll
    for (int f = 0; f < 2; ++f)
#pragma unroll
        for (int j = 0; j < 4; ++j) {
            int c = wc * 64 + j * 16 + lr;
            float b = bias[c];
#pragma unroll
            for (int r = 0; r < 4; ++r) {
                int gr = row0 + wr * 32 + f * 16 + (lane >> 4) * 4 + r;
                if (gr < M) {
                    float v = fmaxf(acc[f][j][r] + b, 0.f);
                    outp[(size_t)gr * D + c] = v;
                }
            }
        }
}

// ---------------------------------------------------------------------------
// Layer-3 GEMM + residual + fused classifier:
//   vif = relu([Aagg|Ax]@W3^T + b3) + resid   (kept in LDS as bf16 hi/lo)
//   out = vif @ Wc^T + bc                     (split-bf16 MFMA, 48-col padded)
// Classifier runs in 2 phases over vif's 64-col halves to fit 48KB LDS.
// ---------------------------------------------------------------------------
__global__ __launch_bounds__(256) void gemm_cls_kernel(const float* __restrict__ Aagg,
                                                       const float* __restrict__ Ax,
                                                       const unsigned short* __restrict__ Whi,
                                                       const unsigned short* __restrict__ Wlo,
                                                       const float* __restrict__ bias,
                                                       const float* __restrict__ residf,
                                                       const unsigned short* __restrict__ Wch,
                                                       const unsigned short* __restrict__ Wcl,
                                                       const float* __restrict__ bc,
                                                       float* __restrict__ outp, int M) {
    __shared__ __align__(16) char smem[49152];
    char* AhB = smem;                 // GEMM: A hi 8KB   | CLS: vif hi 8KB
    char* AlB = smem + 8192;          // GEMM: A lo 8KB   | CLS: vif lo 8KB
    char* WhB = smem + 16384;         // GEMM: W hi 16KB  | CLS: Wc hi 6KB
    char* WlB = smem + 32768;         // GEMM: W lo 16KB  | CLS: Wc lo 6KB (at +32768)

    int tid = threadIdx.x;
    int lane = tid & 63;
    int wid = tid >> 6;
    int wr = wid >> 1;
    int wc = wid & 1;
    int lr = lane & 15;
    int kg = (lane >> 4) * 8;
    int row0 = blockIdx.x * 64;

    f32x4 acc[2][4];
#pragma unroll
    for (int f = 0; f < 2; ++f)
#pragma unroll
        for (int j = 0; j < 4; ++j) acc[f][j] = (f32x4){0.f, 0.f, 0.f, 0.f};

    for (int kt = 0; kt < 4; ++kt) {
        const float* Asrc = (kt < 2) ? Aagg : Ax;
        int kcol = (kt & 1) * 64;
#pragma unroll
        for (int it = 0; it < 2; ++it) {
            int slot = tid + it * 256;
            int row = slot >> 3;
            int k8 = (slot & 7) * 8;
            int gr = row0 + row;
            if (gr >= M) gr = M - 1;
            const float* p = &Asrc[(size_t)gr * D + kcol + k8];
            float4 v0 = *(const float4*)p;
            float4 v1 = *(const float4*)(p + 4);
            float fv[8] = {v0.x, v0.y, v0.z, v0.w, v1.x, v1.y, v1.z, v1.w};
            union { unsigned short u[8]; uint4 q; } ph, pl;
#pragma unroll
            for (int j = 0; j < 8; ++j) {
                unsigned short h = f2bf(fv[j]);
                ph.u[j] = h;
                pl.u[j] = f2bf(fv[j] - bf2f(h));
            }
            int boff = (row << 7) + (k8 << 1);
            boff ^= (row & 7) << 4;
            *(uint4*)(AhB + boff) = ph.q;
            *(uint4*)(AlB + boff) = pl.q;
        }
#pragma unroll
        for (int it = 0; it < 4; ++it) {
            int slot = tid + it * 256;
            int n = slot >> 3;
            int k8 = (slot & 7) * 8;
            size_t gsrc = (size_t)n * 256 + kt * 64 + k8;
            uint4 h = *(const uint4*)&Whi[gsrc];
            uint4 l = *(const uint4*)&Wlo[gsrc];
            int boff = (n << 7) + (k8 << 1);
            boff ^= (n & 7) << 4;
            *(uint4*)(WhB + boff) = h;
            *(uint4*)(WlB + boff) = l;
        }
        __syncthreads();
#pragma unroll
        for (int ks = 0; ks < 2; ++ks) {
            int kk = ks * 32 + kg;
            bf16x8 ah[2], al[2];
#pragma unroll
            for (int f = 0; f < 2; ++f) {
                int row = wr * 32 + f * 16 + lr;
                int boff = (row << 7) + (kk << 1);
                boff ^= (row & 7) << 4;
                ah[f] = *(const bf16x8*)(AhB + boff);
                al[f] = *(const bf16x8*)(AlB + boff);
            }
            bf16x8 bh[4], bl[4];
#pragma unroll
            for (int j = 0; j < 4; ++j) {
                int n = wc * 64 + j * 16 + lr;
                int boff = (n << 7) + (kk << 1);
                boff ^= (n & 7) << 4;
                bh[j] = *(const bf16x8*)(WhB + boff);
                bl[j] = *(const bf16x8*)(WlB + boff);
            }
#pragma unroll
            for (int f = 0; f < 2; ++f)
#pragma unroll
                for (int j = 0; j < 4; ++j) {
                    acc[f][j] = __builtin_amdgcn_mfma_f32_16x16x32_bf16(ah[f], bh[j], acc[f][j], 0, 0, 0);
                    acc[f][j] = __builtin_amdgcn_mfma_f32_16x16x32_bf16(ah[f], bl[j], acc[f][j], 0, 0, 0);
                    acc[f][j] = __builtin_amdgcn_mfma_f32_16x16x32_bf16(al[f], bh[j], acc[f][j], 0, 0, 0);
                }
        }
        __syncthreads();
    }

    // ---- classifier: 2 phases over vif col-halves; acc2 accumulates out[64x48]
    f32x4 acc2[3];
#pragma unroll
    for (int j = 0; j < 3; ++j) acc2[j] = (f32x4){0.f, 0.f, 0.f, 0.f};

    for (int p = 0; p < 2; ++p) {
        // stage Wc half: 48 x 64 bf16 hi/lo
#pragma unroll
        for (int it = 0; it < 2; ++it) {
            int slot = tid + it * 256;
            if (slot < 384) {
                int n = slot >> 3;
                int k8 = (slot & 7) * 8;
                size_t gsrc = (size_t)n * 128 + p * 64 + k8;
                uint4 h = *(const uint4*)&Wch[gsrc];
                uint4 l = *(const uint4*)&Wcl[gsrc];
                int boff = (n << 7) + (k8 << 1);
                boff ^= (n & 7) << 4;
                *(uint4*)(WhB + boff) = h;
                *(uint4*)(WlB + boff) = l;
            }
        }
        // waves owning col-half p write vif = relu(acc+bias)+resid as bf16 hi/lo
        if (wc == p) {
#pragma unroll
            for (int f = 0; f < 2; ++f)
#pragma unroll
                for (int j = 0; j < 4; ++j) {
                    int c = wc * 64 + j * 16 + lr;
                    float b = bias[c];
#pragma unroll
                    for (int r = 0; r < 4; ++r) {
                        int row = wr * 32 + f * 16 + (lane >> 4) * 4 + r;
                        int gr = row0 + row;
                        int gra = (gr < M) ? gr : (M - 1);
                        float v = fmaxf(acc[f][j][r] + b, 0.f);
                        v += residf[(size_t)gra * D + c];
                        int kloc = j * 16 + lr;           // c - p*64
                        int boff = (row << 7) + (kloc << 1);
                        boff ^= (row & 7) << 4;
                        unsigned short h = f2bf(v);
                        *(unsigned short*)(AhB + boff) = h;
                        *(unsigned short*)(AlB + boff) = f2bf(v - bf2f(h));
                    }
                }
        }
        __syncthreads();

        // each wave computes 16 rows x 48 cols over this 64-k half
#pragma unroll
        for (int ks = 0; ks < 2; ++ks) {
            int kk = ks * 32 + kg;
            int row = wid * 16 + lr;
            int boffA = (row << 7) + (kk << 1);
            boffA ^= (row & 7) << 4;
            bf16x8 ah = *(const bf16x8*)(AhB + boffA);
            bf16x8 al = *(const bf16x8*)(AlB + boffA);
#pragma unroll
            for (int j = 0; j < 3; ++j) {
                int n = j * 16 + lr;
                int boffB = (n << 7) + (kk << 1);
                boffB ^= (n & 7) << 4;
                bf16x8 bh = *(const bf16x8*)(WhB + boffB);
                bf16x8 bl = *(const bf16x8*)(WlB + boffB);
                acc2[j] = __builtin_amdgcn_mfma_f32_16x16x32_bf16(ah, bh, acc2[j], 0, 0, 0);
                acc2[j] = __builtin_amdgcn_mfma_f32_16x16x32_bf16(ah, bl, acc2[j], 0, 0, 0);
                acc2[j] = __builtin_amdgcn_mfma_f32_16x16x32_bf16(al, bh, acc2[j], 0, 0, 0);
            }
        }
        __syncthreads();
    }

    // store out[M,40]
#pragma unroll
    for (int j = 0; j < 3; ++j) {
        int c = j * 16 + lr;
        if (c < N_CLS) {
            float b = bc[c];
#pragma unroll
            for (int r = 0; r < 4; ++r) {
                int gr = row0 + wid * 16 + (lane >> 4) * 4 + r;
                if (gr < M) outp[(size_t)gr * N_CLS + c] = acc2[j][r] + b;
            }
        }
    }
}

// ---------------------------------------------------------------------------
extern "C" void kernel_launch(void* const* d_in, const int* in_sizes, int n_in,
                              void* d_out, int out_size, void* d_ws, size_t ws_size,
                              hipStream_t stream) {
    const float* x   = (const float*)d_in[0];
    const int*   ei  = (const int*)d_in[1];
    const float* Wl1 = (const float*)d_in[2];
    const float* bl1 = (const float*)d_in[3];
    const float* Wr1 = (const float*)d_in[4];
    const float* Wl2 = (const float*)d_in[5];
    const float* bl2 = (const float*)d_in[6];
    const float* Wr2 = (const float*)d_in[7];
    const float* Wl3 = (const float*)d_in[8];
    const float* bl3 = (const float*)d_in[9];
    const float* Wr3 = (const float*)d_in[10];
    const float* Wc  = (const float*)d_in[11];
    const float* bc  = (const float*)d_in[12];
    float* out = (float*)d_out;

    char* w = (char*)d_ws;
    size_t off = 0;
    auto carve = [&](size_t bytes) -> void* {
        void* p = w + off;
        off = (off + bytes + 255) & ~(size_t)255;
        return p;
    };
    int*   cnt    = (int*)carve((size_t)N_NODES * 4);
    int*   rs     = (int*)carve((size_t)(N_NODES + 1) * 4);
    int*   cursor = (int*)carve((size_t)N_NODES * 4);
    float* dinv   = (float*)carve((size_t)N_NODES * 4);
    int*   bsum   = (int*)carve(64 * 4);
    int*   boff   = (int*)carve(64 * 4);
    int*   csr    = (int*)carve((size_t)N_EDGES * 4);
    float* aggn   = (float*)carve((size_t)N_NODES * D * 4);   // 25.6 MB
    float* bufA   = (float*)carve((size_t)N_NODES * D * 4);   // 25.6 MB
    float* bufB   = (float*)carve((size_t)N_NODES * D * 4);   // 25.6 MB
    unsigned short* w123h = (unsigned short*)carve(3 * 128 * 256 * 2);
    unsigned short* w123l = (unsigned short*)carve(3 * 128 * 256 * 2);
    unsigned short* wch   = (unsigned short*)carve(48 * 128 * 2);
    unsigned short* wcl   = (unsigned short*)carve(48 * 128 * 2);
    (void)ws_size;

    const int NBLK_SCAN = (N_NODES + 1023) / 1024;           // 49
    const int GRID_E = (N_EDGES + 255) / 256;                // 2344
    const int GRID_N = (N_NODES + 255) / 256;                // 196
    const int GRID_AGG = (N_NODES + 3) / 4;                  // 12500
    const int GRID_GEMM = (N_NODES + 63) / 64;               // 782

    // CSR build + weight splits
    hipMemsetAsync(cnt, 0, (size_t)N_NODES * 4, stream);
    hipLaunchKernelGGL(hist_kernel, dim3(GRID_E), dim3(256), 0, stream, ei, cnt);
    hipLaunchKernelGGL(split_w3_kernel, dim3(384), dim3(256), 0, stream,
                       Wl1, Wr1, Wl2, Wr2, Wl3, Wr3, w123h, w123l);
    hipLaunchKernelGGL(split_wc_kernel, dim3(24), dim3(256), 0, stream, Wc, wch, wcl);
    hipLaunchKernelGGL(scan_block_kernel, dim3(NBLK_SCAN), dim3(1024), 0, stream, cnt, rs, bsum, N_NODES);
    hipLaunchKernelGGL(scan_sums_kernel, dim3(1), dim3(64), 0, stream, bsum, boff, NBLK_SCAN);
    hipLaunchKernelGGL(finalize_kernel, dim3(GRID_N), dim3(256), 0, stream, cnt, rs, cursor, dinv, boff);
    hipLaunchKernelGGL(scatter_kernel, dim3(GRID_E), dim3(256), 0, stream, ei, cursor, csr);

    // Layer 1
    hipLaunchKernelGGL(agg_kernel, dim3(GRID_AGG), dim3(256), 0, stream, x, rs, csr, dinv, aggn);
    hipLaunchKernelGGL(gemm_mfma_kernel, dim3(GRID_GEMM), dim3(256), 0, stream,
                       aggn, x, w123h, w123l, bl1, bufA, N_NODES);
    // Layer 2
    hipLaunchKernelGGL(agg_kernel, dim3(GRID_AGG), dim3(256), 0, stream, bufA, rs, csr, dinv, aggn);
    hipLaunchKernelGGL(gemm_mfma_kernel, dim3(GRID_GEMM), dim3(256), 0, stream,
                       aggn, bufA, w123h + 32768, w123l + 32768, bl2, bufB, N_NODES);
    // Layer 3 + residual + classifier (fused)
    hipLaunchKernelGGL(agg_kernel, dim3(GRID_AGG), dim3(256), 0, stream, bufB, rs, csr, dinv, aggn);
    hipLaunchKernelGGL(gemm_cls_kernel, dim3(GRID_GEMM), dim3(256), 0, stream,
                       aggn, bufB, w123h + 65536, w123l + 65536, bl3, bufB,
                       wch, wcl, bc, out, N_NODES);
}